// Round 13
// baseline (1198.541 us; speedup 1.0000x reference)
//
#include <hip/hip_runtime.h>

#define N_ROWS 65536
#define NE 1024
#define ED 64
#define ERR_GAP 8e-5f

// ---- measurement round: idempotent repeat counts (all writes identical per rep)
#define REP_ZSPLIT 32
#define REP_MFMA   5
#define REP_ZQ     24
#define REP_FILL   6
#define REP_SCAT   64

static const size_t OFF_ZQ = 1;
static const size_t OFF_ME = 1 + 4194304;
static const size_t OFF_IDX = OFF_ME + (size_t)N_ROWS * NE;
#define ME_FLOATS ((size_t)N_ROWS * NE)   // 67108864
#define NBLK_ZQ 16384

#define SC_ZFRAG   0
#define SC_CBFRAG  4194304
#define SC_Z2      4259840
#define SC_PARTIAL 4325376

typedef __attribute__((ext_vector_type(8))) short short8v;
typedef __attribute__((ext_vector_type(4))) float f32x4;

__device__ __forceinline__ unsigned bf16_rne(float v) {
  unsigned u = __float_as_uint(v);
  return (u + 0x7FFFu + ((u >> 16) & 1u)) >> 16;
}

__device__ __forceinline__ void gld16(const void* g, void* l) {
  __builtin_amdgcn_global_load_lds(
      (const __attribute__((address_space(1))) void*)g,
      (__attribute__((address_space(3))) void*)l, 16, 0, 0);
}

// ---- fused: codebook split + e2 (bit-exact) ----
__global__ __launch_bounds__(256) void k_e2cb(const float* __restrict__ cb,
                                              float* __restrict__ e2,
                                              short* __restrict__ cbfrag) {
  const int tid = blockIdx.x * 256 + threadIdx.x;
  const int ct = tid >> 6, lane = tid & 63;
  const int col = ct * 16 + (lane & 15);
  const int k0 = (lane >> 4) * 8;
  const float* __restrict__ ep = cb + (size_t)col * ED + k0;
  short* __restrict__ o = cbfrag + (size_t)ct * 2048 + lane * 8;
  #pragma unroll
  for (int ks = 0; ks < 2; ++ks) {
    short h[8], lo[8];
    #pragma unroll
    for (int i = 0; i < 8; ++i) {
      const float v = ep[ks * 32 + i];
      const unsigned hb = bf16_rne(v);
      const float res = v - __uint_as_float(hb << 16);
      h[i] = (short)hb; lo[i] = (short)bf16_rne(res);
    }
    *(short8v*)(o + (size_t)(0 * 2 + ks) * 512) = *(short8v*)h;
    *(short8v*)(o + (size_t)(1 * 2 + ks) * 512) = *(short8v*)lo;
  }
  if (threadIdx.x < 64) {
    const int j = blockIdx.x * 64 + threadIdx.x;
    const float* __restrict__ e = cb + (size_t)j * ED;
    float r[8];
    #pragma unroll
    for (int i = 0; i < 8; ++i) {
      float v = e[i]; float q = v * v;
      asm volatile("" : "+v"(q)); r[i] = q;
    }
    #pragma unroll
    for (int k = 1; k < 8; ++k)
      #pragma unroll
      for (int i = 0; i < 8; ++i) {
        float v = e[8 * k + i]; float q = v * v;
        asm volatile("" : "+v"(q)); r[i] += q;
      }
    e2[j] = ((r[0] + r[1]) + (r[2] + r[3])) + ((r[4] + r[5]) + (r[6] + r[7]));
  }
}

// ---- fused: z split + z2, repeated REP_ZSPLIT x ----
__global__ __launch_bounds__(256) void k_zsplit(const float* __restrict__ z,
                                                short* __restrict__ zfrag,
                                                float* __restrict__ z2) {
  __shared__ float lz[64][65];
  const int t = threadIdx.x, w = t >> 6, lane = t & 63;
  const int rt = blockIdx.x * 4 + w;
  const int rl = w * 16 + (lane & 15);
  const int n = rt * 16 + (lane & 15);
  const int b = n >> 10, hw = n & 1023;
  const float* __restrict__ zp = z + (size_t)b * 65536 + hw;
  const int k0 = (lane >> 4) * 8;
  short* __restrict__ o = zfrag + (size_t)rt * 2048 + lane * 8;
  #pragma unroll 1
  for (int rep = 0; rep < REP_ZSPLIT; ++rep) {
    #pragma unroll
    for (int ks = 0; ks < 2; ++ks) {
      float vv[8];
      short h[8], lo[8];
      #pragma unroll
      for (int i = 0; i < 8; ++i) {
        const float v = zp[(size_t)(ks * 32 + k0 + i) << 10];
        vv[i] = v;
        const unsigned hb = bf16_rne(v);
        const float res = v - __uint_as_float(hb << 16);
        h[i] = (short)hb; lo[i] = (short)bf16_rne(res);
      }
      #pragma unroll
      for (int i = 0; i < 8; ++i) lz[ks * 32 + k0 + i][rl] = vv[i];
      *(short8v*)(o + (size_t)(0 * 2 + ks) * 512) = *(short8v*)h;
      *(short8v*)(o + (size_t)(1 * 2 + ks) * 512) = *(short8v*)lo;
    }
    __syncthreads();
    if (t < 64) {
      float r[8];
      #pragma unroll
      for (int i = 0; i < 8; ++i) {
        const float v = lz[i][t];
        float q = v * v; asm volatile("" : "+v"(q)); r[i] = q;
      }
      #pragma unroll
      for (int k = 1; k < 8; ++k)
        #pragma unroll
        for (int i = 0; i < 8; ++i) {
          const float v = lz[8 * k + i][t];
          float q = v * v; asm volatile("" : "+v"(q)); r[i] += q;
        }
      z2[blockIdx.x * 64 + t] =
          ((r[0] + r[1]) + (r[2] + r[3])) + ((r[4] + r[5]) + (r[6] + r[7]));
    }
    __syncthreads();   // WAR: protect lz before next rep's writes
  }
}

// ---- MFMA + argmin + inline rescore, repeated REP_MFMA x ----
__global__ __launch_bounds__(256, 4) void k_mfma5(
    const short* __restrict__ zfrag, const short* __restrict__ cbfrag,
    const float* __restrict__ e2g, const float* __restrict__ z2g,
    const float* __restrict__ z, const float* __restrict__ cb,
    float* __restrict__ idxf) {
  __shared__ short lB[2][8192];
  __shared__ float e2l[1024];
  const int t = threadIdx.x, w = t >> 6, lane = t & 63;
  const int row0 = blockIdx.x * 64;

  gld16(e2g + w * 256 + lane * 4, &e2l[w * 256]);

  const int rtg = blockIdx.x * 4 + w;
  short8v a[2][2];
  #pragma unroll
  for (int hl = 0; hl < 2; ++hl)
    #pragma unroll
    for (int ks = 0; ks < 2; ++ks)
      a[hl][ks] = *(const short8v*)(zfrag + (size_t)(rtg * 4 + hl * 2 + ks) * 512 + lane * 8);

  float z2r[4];
  #pragma unroll
  for (int reg = 0; reg < 4; ++reg)
    z2r[reg] = z2g[row0 + w * 16 + (lane >> 4) * 4 + reg];

  #pragma unroll 1
  for (int rep = 0; rep < REP_MFMA; ++rep) {
    #pragma unroll
    for (int i = 0; i < 4; ++i) {
      const int s = w * 4 + i;
      gld16(cbfrag + s * 512 + lane * 8, &lB[0][s * 512]);
    }

    float Tm[4], Ts[4]; int Tb[4];
    #pragma unroll
    for (int reg = 0; reg < 4; ++reg) { Tm[reg] = 1e30f; Ts[reg] = 1e30f; Tb[reg] = 0; }

    __syncthreads();

    int buf = 0;
    for (int c = 0; c < 16; ++c) {
      if (c < 15) {
        #pragma unroll
        for (int i = 0; i < 4; ++i) {
          const int s = w * 4 + i;
          gld16(cbfrag + (size_t)(c + 1) * 8192 + s * 512 + lane * 8,
                &lB[buf ^ 1][s * 512]);
        }
      }
      #pragma unroll 1
      for (int ctl = 0; ctl < 4; ++ctl) {
        short8v bfr[2][2];
        #pragma unroll
        for (int hl = 0; hl < 2; ++hl)
          #pragma unroll
          for (int ks = 0; ks < 2; ++ks)
            bfr[hl][ks] = *(const short8v*)&lB[buf][(ctl * 4 + hl * 2 + ks) * 512 + lane * 8];

        f32x4 acc = (f32x4)(0.0f);
        #pragma unroll
        for (int p = 0; p < 3; ++p) {
          const int pa = (p == 2) ? 1 : 0;
          const int pb = (p == 1) ? 1 : 0;
          #pragma unroll
          for (int ks = 0; ks < 2; ++ks)
            acc = __builtin_amdgcn_mfma_f32_16x16x32_bf16(a[pa][ks], bfr[pb][ks], acc, 0, 0, 0);
        }
        const int j = c * 64 + ctl * 16 + (lane & 15);
        const float e2v = e2l[j];
        #pragma unroll
        for (int reg = 0; reg < 4; ++reg) {
          const float dd = (z2r[reg] + e2v) - 2.0f * acc[reg];
          if (dd < Tm[reg]) { Ts[reg] = Tm[reg]; Tm[reg] = dd; Tb[reg] = j; }
          else { Ts[reg] = fminf(Ts[reg], dd); }
        }
      }
      __syncthreads();
      buf ^= 1;
    }

    bool flg[4];
    #pragma unroll
    for (int reg = 0; reg < 4; ++reg) {
      float m = Tm[reg], s = Ts[reg]; int bi = Tb[reg];
      #pragma unroll
      for (int off = 1; off < 16; off <<= 1) {
        const float om = __shfl_xor(m, off, 64);
        const float os = __shfl_xor(s, off, 64);
        const int   oi = __shfl_xor(bi, off, 64);
        if (om < m || (om == m && oi < bi)) { s = fminf(m, os); m = om; bi = oi; }
        else { s = fminf(s, om); }
      }
      flg[reg] = (s - m < ERR_GAP);
      if ((lane & 15) == 0 && !flg[reg]) {
        const int n = row0 + w * 16 + (lane >> 4) * 4 + reg;
        idxf[n] = (float)bi;
      }
    }

    #pragma unroll 1
    for (int reg = 0; reg < 4; ++reg) {
      unsigned long long mm = __ballot(((lane & 15) == 0) && flg[reg]);
      while (mm) {
        const int bit = __ffsll((long long)mm) - 1; mm &= mm - 1;
        const int n = row0 + w * 16 + (bit >> 4) * 4 + reg;
        const int b = n >> 10, hw = n & 1023;
        const float zv = z[(size_t)b * 65536 + ((size_t)lane << 10) + hw];
        float zb[64];
        #pragma unroll
        for (int k = 0; k < 64; ++k) zb[k] = __shfl(zv, k, 64);
        const float z2v = z2g[n];
        float bm = 1e30f; int bix = 0;
        for (int q = 0; q < 16; ++q) {
          const int j = lane * 16 + q;
          const float* __restrict__ e = cb + (size_t)j * ED;
          float acl = 0.0f;
          #pragma unroll
          for (int k = 0; k < ED; ++k) acl = fmaf(zb[k], e[k], acl);
          const float d = (z2v + e2g[j]) - 2.0f * acl;
          if (d < bm) { bm = d; bix = j; }
        }
        #pragma unroll
        for (int off = 1; off < 64; off <<= 1) {
          const float om = __shfl_xor(bm, off, 64);
          const int   oi = __shfl_xor(bix, off, 64);
          if (om < bm || (om == bm && oi < bix)) { bm = om; bix = oi; }
        }
        if (lane == 0) idxf[n] = (float)bix;
      }
    }
    __syncthreads();   // re-converge before next rep's lB[0] staging
  }
}

// ---- z_q gather + loss partial, repeated REP_ZQ x ----
__global__ __launch_bounds__(256) void k_zq(const float* __restrict__ z,
    const float* __restrict__ cb, const float* __restrict__ idxf,
    float* __restrict__ zq, float* __restrict__ partial) {
  __shared__ float sh[4];
  const int o = blockIdx.x * 256 + threadIdx.x;
  const int b = o >> 16;
  const int d = (o >> 10) & 63;
  const int hw = o & 1023;
  const int n = (b << 10) + hw;
  #pragma unroll 1
  for (int rep = 0; rep < REP_ZQ; ++rep) {
    const int idx = (int)idxf[n];
    const float v = cb[(size_t)idx * ED + d];
    zq[o] = v;
    const float diff = z[o] - v;
    float s = diff * diff;
    #pragma unroll
    for (int off = 32; off > 0; off >>= 1) s += __shfl_xor(s, off, 64);
    if ((threadIdx.x & 63) == 0) sh[threadIdx.x >> 6] = s;
    __syncthreads();
    if (threadIdx.x == 0)
      partial[blockIdx.x] = (sh[0] + sh[1]) + (sh[2] + sh[3]);
    __syncthreads();   // WAR on sh before next rep
  }
}

__global__ void k_loss(const float* __restrict__ partial, float* __restrict__ out0) {
  const int t = threadIdx.x;
  double s = 0.0;
  #pragma unroll
  for (int k = 0; k < NBLK_ZQ / 256; ++k) s += (double)partial[t + (k << 8)];
  #pragma unroll
  for (int off = 32; off > 0; off >>= 1) s += __shfl_xor(s, off, 64);
  __shared__ double sh[4];
  if ((t & 63) == 0) sh[t >> 6] = s;
  __syncthreads();
  if (t == 0)
    out0[0] = (float)(1.25 * ((sh[0] + sh[1]) + (sh[2] + sh[3])) / 4194304.0);
}

// ---- zero-fill, repeated REP_FILL x ----
__global__ __launch_bounds__(256) void k_fill(float* __restrict__ me) {
  const size_t n4 = (ME_FLOATS - 3) >> 2;
  float4* __restrict__ p4 = reinterpret_cast<float4*>(me + 3);
  const size_t stride = (size_t)gridDim.x * blockDim.x;
  const float4 zero4 = make_float4(0.f, 0.f, 0.f, 0.f);
  #pragma unroll 1
  for (int rep = 0; rep < REP_FILL; ++rep) {
    for (size_t i = blockIdx.x * (size_t)blockDim.x + threadIdx.x; i < n4; i += stride)
      p4[i] = zero4;
    if (blockIdx.x == 0 && threadIdx.x == 0) {
      me[0] = 0.f; me[1] = 0.f; me[2] = 0.f;
      me[ME_FLOATS - 1] = 0.f;
    }
  }
}

// ---- scatter, repeated REP_SCAT x ----
__global__ void k_scatter(const float* __restrict__ idxf, float* __restrict__ me) {
  const int n = blockIdx.x * 256 + threadIdx.x;
  #pragma unroll 1
  for (int rep = 0; rep < REP_SCAT; ++rep) {
    const int idx = (int)idxf[n];
    me[(size_t)n * NE + idx] = 1.0f;
  }
}

extern "C" void kernel_launch(void* const* d_in, const int* in_sizes, int n_in,
                              void* d_out, int out_size, void* d_ws, size_t ws_size,
                              hipStream_t stream) {
  const float* z  = (const float*)d_in[0];
  const float* cb = (const float*)d_in[1];
  float* out  = (float*)d_out;
  float* zq   = out + OFF_ZQ;
  float* me   = out + OFF_ME;
  float* idxf = out + OFF_IDX;
  float* base = me + 3;
  short* zfrag   = (short*)(base + SC_ZFRAG);
  short* cbfrag  = (short*)(base + SC_CBFRAG);
  float* z2      = base + SC_Z2;
  float* partial = base + SC_PARTIAL;
  float* e2  = (float*)((char*)d_ws + 16);

  k_e2cb<<<16, 256, 0, stream>>>(cb, e2, cbfrag);
  k_zsplit<<<1024, 256, 0, stream>>>(z, zfrag, z2);
  k_mfma5<<<1024, 256, 0, stream>>>(zfrag, cbfrag, e2, z2, z, cb, idxf);
  k_zq<<<NBLK_ZQ, 256, 0, stream>>>(z, cb, idxf, zq, partial);
  k_loss<<<1, 256, 0, stream>>>(partial, out);
  k_fill<<<2048, 256, 0, stream>>>(me);
  k_scatter<<<N_ROWS / 256, 256, 0, stream>>>(idxf, me);
}

// Round 14
// 192.753 us; speedup vs baseline: 6.2180x; 6.2180x over previous
//
#include <hip/hip_runtime.h>

#define N_ROWS 65536
#define NE 1024
#define ED 64
#define ERR_GAP 8e-5f

static const size_t OFF_ZQ = 1;
static const size_t OFF_ME = 1 + 4194304;
static const size_t OFF_IDX = OFF_ME + (size_t)N_ROWS * NE;
#define ME_FLOATS ((size_t)N_ROWS * NE)   // 67108864
#define NBLK_ZQ 16384

// scratch (float offsets) from base = me+3 (16B aligned); consumed before k_fill.
#define SC_ZFRAG   0           // 4194304 floats (8.4M bf16 shorts)
#define SC_CBFRAG  4194304     // 65536 floats = 256KB
#define SC_Z2      4259840     // 65536
#define SC_PARTIAL 4325376     // 16384
#define SC_FLAG    4341760     // 65536 ints

typedef __attribute__((ext_vector_type(8))) short short8v;
typedef __attribute__((ext_vector_type(4))) float f32x4;

__device__ __forceinline__ unsigned bf16_rne(float v) {
  unsigned u = __float_as_uint(v);
  return (u + 0x7FFFu + ((u >> 16) & 1u)) >> 16;
}

__device__ __forceinline__ void gld16(const void* g, void* l) {
  __builtin_amdgcn_global_load_lds(
      (const __attribute__((address_space(1))) void*)g,
      (__attribute__((address_space(3))) void*)l, 16, 0, 0);
}

// ---- fused: codebook split (B-fragment order) + e2 (bit-exact) ----
__global__ __launch_bounds__(256) void k_e2cb(const float* __restrict__ cb,
                                              float* __restrict__ e2,
                                              short* __restrict__ cbfrag) {
  const int tid = blockIdx.x * 256 + threadIdx.x;
  const int ct = tid >> 6, lane = tid & 63;
  const int col = ct * 16 + (lane & 15);
  const int k0 = (lane >> 4) * 8;
  const float* __restrict__ ep = cb + (size_t)col * ED + k0;
  short* __restrict__ o = cbfrag + (size_t)ct * 2048 + lane * 8;
  #pragma unroll
  for (int ks = 0; ks < 2; ++ks) {
    short h[8], lo[8];
    #pragma unroll
    for (int i = 0; i < 8; ++i) {
      const float v = ep[ks * 32 + i];
      const unsigned hb = bf16_rne(v);
      const float res = v - __uint_as_float(hb << 16);
      h[i] = (short)hb; lo[i] = (short)bf16_rne(res);
    }
    *(short8v*)(o + (size_t)(0 * 2 + ks) * 512) = *(short8v*)h;
    *(short8v*)(o + (size_t)(1 * 2 + ks) * 512) = *(short8v*)lo;
  }
  if (threadIdx.x < 64) {
    const int j = blockIdx.x * 64 + threadIdx.x;
    const float* __restrict__ e = cb + (size_t)j * ED;
    float r[8];
    #pragma unroll
    for (int i = 0; i < 8; ++i) {
      float v = e[i]; float q = v * v;
      asm volatile("" : "+v"(q)); r[i] = q;
    }
    #pragma unroll
    for (int k = 1; k < 8; ++k)
      #pragma unroll
      for (int i = 0; i < 8; ++i) {
        float v = e[8 * k + i]; float q = v * v;
        asm volatile("" : "+v"(q)); r[i] += q;
      }
    e2[j] = ((r[0] + r[1]) + (r[2] + r[3])) + ((r[4] + r[5]) + (r[6] + r[7]));
  }
}

// ---- fused: z split (A-fragment order) + z2 (bit-exact pairwise via LDS) ----
__global__ __launch_bounds__(256) void k_zsplit(const float* __restrict__ z,
                                                short* __restrict__ zfrag,
                                                float* __restrict__ z2) {
  __shared__ float lz[64][65];
  const int t = threadIdx.x, w = t >> 6, lane = t & 63;
  const int rt = blockIdx.x * 4 + w;
  const int rl = w * 16 + (lane & 15);
  const int n = rt * 16 + (lane & 15);
  const int b = n >> 10, hw = n & 1023;
  const float* __restrict__ zp = z + (size_t)b * 65536 + hw;
  const int k0 = (lane >> 4) * 8;
  short* __restrict__ o = zfrag + (size_t)rt * 2048 + lane * 8;
  #pragma unroll
  for (int ks = 0; ks < 2; ++ks) {
    float vv[8];
    short h[8], lo[8];
    #pragma unroll
    for (int i = 0; i < 8; ++i) {
      const float v = zp[(size_t)(ks * 32 + k0 + i) << 10];
      vv[i] = v;
      const unsigned hb = bf16_rne(v);
      const float res = v - __uint_as_float(hb << 16);
      h[i] = (short)hb; lo[i] = (short)bf16_rne(res);
    }
    #pragma unroll
    for (int i = 0; i < 8; ++i) lz[ks * 32 + k0 + i][rl] = vv[i];
    *(short8v*)(o + (size_t)(0 * 2 + ks) * 512) = *(short8v*)h;
    *(short8v*)(o + (size_t)(1 * 2 + ks) * 512) = *(short8v*)lo;
  }
  __syncthreads();
  if (t < 64) {
    float r[8];
    #pragma unroll
    for (int i = 0; i < 8; ++i) {
      const float v = lz[i][t];
      float q = v * v; asm volatile("" : "+v"(q)); r[i] = q;
    }
    #pragma unroll
    for (int k = 1; k < 8; ++k)
      #pragma unroll
      for (int i = 0; i < 8; ++i) {
        const float v = lz[8 * k + i][t];
        float q = v * v; asm volatile("" : "+v"(q)); r[i] += q;
      }
    z2[blockIdx.x * 64 + t] =
        ((r[0] + r[1]) + (r[2] + r[3])) + ((r[4] + r[5]) + (r[6] + r[7]));
  }
}

// ---- MFMA distance + (min,2nd,argmin) + per-row flag — r11-measured clean kernel ----
__global__ __launch_bounds__(256, 4) void k_mfma4(
    const short* __restrict__ zfrag, const short* __restrict__ cbfrag,
    const float* __restrict__ e2g, const float* __restrict__ z2g,
    float* __restrict__ idxf, int* __restrict__ flag) {
  __shared__ short lB[2][8192];
  __shared__ float e2l[1024];
  const int t = threadIdx.x, w = t >> 6, lane = t & 63;
  const int row0 = blockIdx.x * 64;

  #pragma unroll
  for (int i = 0; i < 4; ++i) {
    const int s = w * 4 + i;
    gld16(cbfrag + s * 512 + lane * 8, &lB[0][s * 512]);
  }
  gld16(e2g + w * 256 + lane * 4, &e2l[w * 256]);

  const int rtg = blockIdx.x * 4 + w;
  short8v a[2][2];
  #pragma unroll
  for (int hl = 0; hl < 2; ++hl)
    #pragma unroll
    for (int ks = 0; ks < 2; ++ks)
      a[hl][ks] = *(const short8v*)(zfrag + (size_t)(rtg * 4 + hl * 2 + ks) * 512 + lane * 8);

  float z2r[4];
  #pragma unroll
  for (int reg = 0; reg < 4; ++reg)
    z2r[reg] = z2g[row0 + w * 16 + (lane >> 4) * 4 + reg];

  float Tm[4], Ts[4]; int Tb[4];
  #pragma unroll
  for (int reg = 0; reg < 4; ++reg) { Tm[reg] = 1e30f; Ts[reg] = 1e30f; Tb[reg] = 0; }

  __syncthreads();

  int buf = 0;
  for (int c = 0; c < 16; ++c) {
    if (c < 15) {
      #pragma unroll
      for (int i = 0; i < 4; ++i) {
        const int s = w * 4 + i;
        gld16(cbfrag + (size_t)(c + 1) * 8192 + s * 512 + lane * 8,
              &lB[buf ^ 1][s * 512]);
      }
    }
    #pragma unroll 1
    for (int ctl = 0; ctl < 4; ++ctl) {
      short8v bfr[2][2];
      #pragma unroll
      for (int hl = 0; hl < 2; ++hl)
        #pragma unroll
        for (int ks = 0; ks < 2; ++ks)
          bfr[hl][ks] = *(const short8v*)&lB[buf][(ctl * 4 + hl * 2 + ks) * 512 + lane * 8];

      f32x4 acc = (f32x4)(0.0f);
      // pairs (a_hl,b_hl): (h,h) (h,l) (l,h); ks inner — same order as r8-r13
      #pragma unroll
      for (int p = 0; p < 3; ++p) {
        const int pa = (p == 2) ? 1 : 0;
        const int pb = (p == 1) ? 1 : 0;
        #pragma unroll
        for (int ks = 0; ks < 2; ++ks)
          acc = __builtin_amdgcn_mfma_f32_16x16x32_bf16(a[pa][ks], bfr[pb][ks], acc, 0, 0, 0);
      }
      const int j = c * 64 + ctl * 16 + (lane & 15);
      const float e2v = e2l[j];
      #pragma unroll
      for (int reg = 0; reg < 4; ++reg) {
        const float dd = (z2r[reg] + e2v) - 2.0f * acc[reg];
        if (dd < Tm[reg]) { Ts[reg] = Tm[reg]; Tm[reg] = dd; Tb[reg] = j; }
        else { Ts[reg] = fminf(Ts[reg], dd); }
      }
    }
    __syncthreads();
    buf ^= 1;
  }

  #pragma unroll
  for (int reg = 0; reg < 4; ++reg) {
    float m = Tm[reg], s = Ts[reg]; int bi = Tb[reg];
    #pragma unroll
    for (int off = 1; off < 16; off <<= 1) {
      const float om = __shfl_xor(m, off, 64);
      const float os = __shfl_xor(s, off, 64);
      const int   oi = __shfl_xor(bi, off, 64);
      if (om < m || (om == m && oi < bi)) { s = fminf(m, os); m = om; bi = oi; }
      else { s = fminf(s, om); }
    }
    if ((lane & 15) == 0) {
      const int n = row0 + w * 16 + (lane >> 4) * 4 + reg;
      idxf[n] = (float)bi;
      flag[n] = (s - m < ERR_GAP) ? 1 : 0;
    }
  }
}

// ---- exact rescore, block-parallel: 256 threads per flagged row ----
// z-row in LDS (broadcast reads), 4 codes/thread = 4 independent sequential
// 64-FMA chains (bit-exact BLAS order), NO per-thread arrays -> no scratch.
// Two-level lexicographic (value,index) reduce == numpy first-index argmin.
__global__ __launch_bounds__(256) void k_exact2(const float* __restrict__ z,
    const float* __restrict__ cb, const float* __restrict__ e2,
    const float* __restrict__ z2g, const int* __restrict__ flag,
    float* __restrict__ idxf) {
  __shared__ float zrow[64];
  __shared__ unsigned long long maskS;
  __shared__ float redM[4];
  __shared__ int   redI[4];
  const int t = threadIdx.x, w = t >> 6, lane = t & 63;
  const int row0 = blockIdx.x * 64;
  if (t < 64) {
    const unsigned long long mk = __ballot(flag[row0 + lane] != 0);
    if (lane == 0) maskS = mk;
  }
  __syncthreads();
  unsigned long long mask = maskS;
  while (mask) {
    const int bit = __ffsll((long long)mask) - 1; mask &= mask - 1;
    const int n = row0 + bit;
    const int b = n >> 10, hw = n & 1023;
    if (t < 64) zrow[t] = z[(size_t)b * 65536 + ((size_t)t << 10) + hw];
    __syncthreads();
    const float z2v = z2g[n];
    const float* __restrict__ e0 = cb + (size_t)t * 256;   // rows 4t..4t+3
    float a0 = 0.f, a1 = 0.f, a2 = 0.f, a3 = 0.f;
    #pragma unroll
    for (int k = 0; k < 64; ++k) {
      const float zk = zrow[k];
      a0 = fmaf(zk, e0[k],       a0);   // sequential chain, k ascending (bit-exact)
      a1 = fmaf(zk, e0[64 + k],  a1);
      a2 = fmaf(zk, e0[128 + k], a2);
      a3 = fmaf(zk, e0[192 + k], a3);
    }
    float bm = 1e30f; int bi = 0;
    const float d0 = (z2v + e2[t * 4 + 0]) - 2.0f * a0;
    const float d1 = (z2v + e2[t * 4 + 1]) - 2.0f * a1;
    const float d2 = (z2v + e2[t * 4 + 2]) - 2.0f * a2;
    const float d3 = (z2v + e2[t * 4 + 3]) - 2.0f * a3;
    if (d0 < bm) { bm = d0; bi = t * 4 + 0; }   // ascending j, strict <
    if (d1 < bm) { bm = d1; bi = t * 4 + 1; }
    if (d2 < bm) { bm = d2; bi = t * 4 + 2; }
    if (d3 < bm) { bm = d3; bi = t * 4 + 3; }
    #pragma unroll
    for (int off = 1; off < 64; off <<= 1) {
      const float om = __shfl_xor(bm, off, 64);
      const int   oi = __shfl_xor(bi, off, 64);
      if (om < bm || (om == bm && oi < bi)) { bm = om; bi = oi; }
    }
    if (lane == 0) { redM[w] = bm; redI[w] = bi; }
    __syncthreads();
    if (t == 0) {
      float m = redM[0]; int i0 = redI[0];
      #pragma unroll
      for (int ww = 1; ww < 4; ++ww) {
        if (redM[ww] < m || (redM[ww] == m && redI[ww] < i0)) { m = redM[ww]; i0 = redI[ww]; }
      }
      idxf[n] = (float)i0;
    }
    __syncthreads();   // protect zrow/red before next flagged row
  }
}

// ---- z_q gather + per-block loss partial ----
__global__ __launch_bounds__(256) void k_zq(const float* __restrict__ z,
    const float* __restrict__ cb, const float* __restrict__ idxf,
    float* __restrict__ zq, float* __restrict__ partial) {
  const int o = blockIdx.x * 256 + threadIdx.x;
  const int b = o >> 16;
  const int d = (o >> 10) & 63;
  const int hw = o & 1023;
  const int n = (b << 10) + hw;
  const int idx = (int)idxf[n];
  const float v = cb[(size_t)idx * ED + d];
  zq[o] = v;
  const float diff = z[o] - v;
  float s = diff * diff;
  #pragma unroll
  for (int off = 32; off > 0; off >>= 1) s += __shfl_xor(s, off, 64);
  __shared__ float sh[4];
  if ((threadIdx.x & 63) == 0) sh[threadIdx.x >> 6] = s;
  __syncthreads();
  if (threadIdx.x == 0)
    partial[blockIdx.x] = (sh[0] + sh[1]) + (sh[2] + sh[3]);
}

__global__ void k_loss(const float* __restrict__ partial, float* __restrict__ out0) {
  const int t = threadIdx.x;
  double s = 0.0;
  #pragma unroll
  for (int k = 0; k < NBLK_ZQ / 256; ++k) s += (double)partial[t + (k << 8)];
  #pragma unroll
  for (int off = 32; off > 0; off >>= 1) s += __shfl_xor(s, off, 64);
  __shared__ double sh[4];
  if ((t & 63) == 0) sh[t >> 6] = s;
  __syncthreads();
  if (t == 0)
    out0[0] = (float)(1.25 * ((sh[0] + sh[1]) + (sh[2] + sh[3])) / 4194304.0);
}

// ---- zero-fill the one-hot region (write-BW floor) ----
__global__ __launch_bounds__(256) void k_fill(float* __restrict__ me) {
  const size_t n4 = (ME_FLOATS - 3) >> 2;
  float4* __restrict__ p4 = reinterpret_cast<float4*>(me + 3);
  const size_t stride = (size_t)gridDim.x * blockDim.x;
  const float4 zero4 = make_float4(0.f, 0.f, 0.f, 0.f);
  for (size_t i = blockIdx.x * (size_t)blockDim.x + threadIdx.x; i < n4; i += stride)
    p4[i] = zero4;
  if (blockIdx.x == 0 && threadIdx.x == 0) {
    me[0] = 0.f; me[1] = 0.f; me[2] = 0.f;
    me[ME_FLOATS - 1] = 0.f;
  }
}

__global__ void k_scatter(const float* __restrict__ idxf, float* __restrict__ me) {
  const int n = blockIdx.x * 256 + threadIdx.x;
  const int idx = (int)idxf[n];
  me[(size_t)n * NE + idx] = 1.0f;
}

extern "C" void kernel_launch(void* const* d_in, const int* in_sizes, int n_in,
                              void* d_out, int out_size, void* d_ws, size_t ws_size,
                              hipStream_t stream) {
  const float* z  = (const float*)d_in[0];
  const float* cb = (const float*)d_in[1];
  float* out  = (float*)d_out;
  float* zq   = out + OFF_ZQ;
  float* me   = out + OFF_ME;
  float* idxf = out + OFF_IDX;
  float* base = me + 3;
  short* zfrag   = (short*)(base + SC_ZFRAG);
  short* cbfrag  = (short*)(base + SC_CBFRAG);
  float* z2      = base + SC_Z2;
  float* partial = base + SC_PARTIAL;
  int*   flag    = (int*)(base + SC_FLAG);
  float* e2  = (float*)((char*)d_ws + 16);

  k_e2cb<<<16, 256, 0, stream>>>(cb, e2, cbfrag);
  k_zsplit<<<1024, 256, 0, stream>>>(z, zfrag, z2);
  k_mfma4<<<1024, 256, 0, stream>>>(zfrag, cbfrag, e2, z2, idxf, flag);
  k_exact2<<<1024, 256, 0, stream>>>(z, cb, e2, z2, flag, idxf);
  k_zq<<<NBLK_ZQ, 256, 0, stream>>>(z, cb, idxf, zq, partial);
  k_loss<<<1, 256, 0, stream>>>(partial, out);
  k_fill<<<2048, 256, 0, stream>>>(me);
  k_scatter<<<N_ROWS / 256, 256, 0, stream>>>(idxf, me);
}